// Round 1
// baseline (646.309 us; speedup 1.0000x reference)
//
#include <hip/hip_runtime.h>
#include <hip/hip_bf16.h>

#define T_SEQ 2048
#define DMODEL 1024
#define NHEAD 16
#define DHEAD 64
#define NBATCH 2
#define NROWS (NBATCH * T_SEQ)   // 4096
#define DFFN (4 * DMODEL)        // 4096

typedef __bf16 bf16;
typedef __bf16 bf16x8 __attribute__((ext_vector_type(8)));
typedef __bf16 bf16x4 __attribute__((ext_vector_type(4)));
typedef float f32x4 __attribute__((ext_vector_type(4)));

// ---------------------------------------------------------------- transpose W [K,N] f32 -> Wt [N,K] bf16
__global__ void transpose_f32_to_bf16(const float* __restrict__ in, bf16* __restrict__ out,
                                      int K, int N) {
    __shared__ float tile[32][33];
    int k0 = blockIdx.y * 32, n0 = blockIdx.x * 32;
    int tx = threadIdx.x & 31, ty = threadIdx.x >> 5;  // ty 0..7
#pragma unroll
    for (int i = 0; i < 32; i += 8)
        tile[ty + i][tx] = in[(size_t)(k0 + ty + i) * N + n0 + tx];
    __syncthreads();
#pragma unroll
    for (int i = 0; i < 32; i += 8)
        out[(size_t)(n0 + ty + i) * K + k0 + tx] = (bf16)tile[tx][ty + i];
}

// ---------------------------------------------------------------- f32 -> bf16 cast (vectorized x4)
__global__ void cast_f32_bf16(const float* __restrict__ in, bf16* __restrict__ out, int n4) {
    int i = blockIdx.x * blockDim.x + threadIdx.x;
    if (i >= n4) return;
    float4 v = reinterpret_cast<const float4*>(in)[i];
    bf16x4 o;
    o[0] = (bf16)v.x; o[1] = (bf16)v.y; o[2] = (bf16)v.z; o[3] = (bf16)v.w;
    reinterpret_cast<bf16x4*>(out)[i] = o;
}

// ---------------------------------------------------------------- LayerNorm row (D=1024), out bf16
__global__ void layernorm_bf16(const float* __restrict__ x, const float* __restrict__ w,
                               const float* __restrict__ b, bf16* __restrict__ out) {
    int row = blockIdx.x;
    int t = threadIdx.x;  // 256 threads, 4 f32 each
    const float* xr = x + (size_t)row * DMODEL;
    float4 v = reinterpret_cast<const float4*>(xr)[t];
    float s = v.x + v.y + v.z + v.w;
    float sq = v.x * v.x + v.y * v.y + v.z * v.z + v.w * v.w;
#pragma unroll
    for (int off = 1; off < 64; off <<= 1) {
        s += __shfl_xor(s, off);
        sq += __shfl_xor(sq, off);
    }
    __shared__ float ss[4], ssq[4];
    int wid = t >> 6;
    if ((t & 63) == 0) { ss[wid] = s; ssq[wid] = sq; }
    __syncthreads();
    s = ss[0] + ss[1] + ss[2] + ss[3];
    sq = ssq[0] + ssq[1] + ssq[2] + ssq[3];
    float mu = s * (1.0f / DMODEL);
    float var = sq * (1.0f / DMODEL) - mu * mu;
    float rstd = rsqrtf(var + 1e-5f);
    float4 wv = reinterpret_cast<const float4*>(w)[t];
    float4 bv = reinterpret_cast<const float4*>(b)[t];
    bf16x4 o;
    o[0] = (bf16)((v.x - mu) * rstd * wv.x + bv.x);
    o[1] = (bf16)((v.y - mu) * rstd * wv.y + bv.y);
    o[2] = (bf16)((v.z - mu) * rstd * wv.z + bv.z);
    o[3] = (bf16)((v.w - mu) * rstd * wv.w + bv.w);
    reinterpret_cast<bf16x4*>(out + (size_t)row * DMODEL)[t] = o;
}

// ---------------------------------------------------------------- GEMM: C[M,N] = A[M,K](bf16) * Bt[N,K](bf16)^T + bias
// MODE 0: out bf16   MODE 1: out bf16 with exact GELU   MODE 2: out f32 = v + bias + res
template <int MODE>
__global__ __launch_bounds__(256, 2) void gemm_bf16(const bf16* __restrict__ A,
                                                    const bf16* __restrict__ Bt,
                                                    const float* __restrict__ bias,
                                                    const float* __restrict__ res,
                                                    void* __restrict__ Cout,
                                                    int M, int N, int K) {
    constexpr int BK = 32;
    __shared__ bf16 As[128][BK + 8];
    __shared__ bf16 Bs[128][BK + 8];
    int m0 = blockIdx.y * 128, n0 = blockIdx.x * 128;
    int t = threadIdx.x;
    int lane = t & 63, w = t >> 6;
    int wr = w >> 1, wc = w & 1;
    int l15 = lane & 15, lg = lane >> 4;
    f32x4 acc[4][4] = {};

    for (int kb = 0; kb < K; kb += BK) {
        __syncthreads();
#pragma unroll
        for (int i = 0; i < 2; i++) {
            int cid = t + i * 256;           // 512 chunks of 8 bf16
            int r = cid >> 2, off = (cid & 3) << 3;
            *reinterpret_cast<bf16x8*>(&As[r][off]) =
                *reinterpret_cast<const bf16x8*>(&A[(size_t)(m0 + r) * K + kb + off]);
            *reinterpret_cast<bf16x8*>(&Bs[r][off]) =
                *reinterpret_cast<const bf16x8*>(&Bt[(size_t)(n0 + r) * K + kb + off]);
        }
        __syncthreads();
        bf16x8 af[4], bfr[4];
#pragma unroll
        for (int i = 0; i < 4; i++)
            af[i] = *reinterpret_cast<const bf16x8*>(&As[wr * 64 + i * 16 + l15][lg * 8]);
#pragma unroll
        for (int i = 0; i < 4; i++)
            bfr[i] = *reinterpret_cast<const bf16x8*>(&Bs[wc * 64 + i * 16 + l15][lg * 8]);
#pragma unroll
        for (int mi = 0; mi < 4; mi++)
#pragma unroll
            for (int ni = 0; ni < 4; ni++)
                acc[mi][ni] = __builtin_amdgcn_mfma_f32_16x16x32_bf16(af[mi], bfr[ni], acc[mi][ni], 0, 0, 0);
    }

#pragma unroll
    for (int mi = 0; mi < 4; mi++) {
#pragma unroll
        for (int ni = 0; ni < 4; ni++) {
            int col = n0 + wc * 64 + ni * 16 + l15;
            float bsv = bias[col];
#pragma unroll
            for (int r = 0; r < 4; r++) {
                int row = m0 + wr * 64 + mi * 16 + lg * 4 + r;
                float v = acc[mi][ni][r] + bsv;
                size_t idx = (size_t)row * N + col;
                if (MODE == 0) {
                    ((bf16*)Cout)[idx] = (bf16)v;
                } else if (MODE == 1) {
                    float g = 0.5f * v * (1.0f + erff(v * 0.70710678118654752f));
                    ((bf16*)Cout)[idx] = (bf16)g;
                } else {
                    ((float*)Cout)[idx] = v + res[idx];
                }
            }
        }
    }
}

// ---------------------------------------------------------------- flash attention, dual-QK (qk-dim 128), causal
// grid: (T/64, B*H); block 256 (4 waves, 16 q-rows each)
__global__ __launch_bounds__(256, 2) void flash_attn(const bf16* __restrict__ Qc,
                                                     const bf16* __restrict__ Kc,
                                                     const bf16* __restrict__ Qs,
                                                     const bf16* __restrict__ Ks,
                                                     const bf16* __restrict__ V,
                                                     bf16* __restrict__ O) {
    __shared__ bf16 Klds[64][128 + 8];  // qk-dim concat [Kc|Ks]
    __shared__ bf16 Vt[64][64 + 8];     // transposed: [d][k]
    __shared__ bf16 Plds[4][16][40];    // per-wave P tile [q][k32]

    int bh = blockIdx.y;
    int b = bh >> 4, h = bh & 15;
    int q0 = blockIdx.x * 64;
    int t = threadIdx.x;
    int w = t >> 6, lane = t & 63;
    int l15 = lane & 15, lg = lane >> 4;
    int qg = q0 + w * 16 + l15;  // this lane's q row (for softmax stats / B-operand col)

    // Q' fragments (qk-dim 128 = 4 chunks of 32), kept in registers
    size_t qbase = ((size_t)(b * T_SEQ + qg)) * DMODEL + h * DHEAD;
    bf16x8 qf[4];
#pragma unroll
    for (int c = 0; c < 4; c++) {
        int dd = c * 32 + lg * 8;
        const bf16* src = (dd < 64) ? (Qc + qbase + dd) : (Qs + qbase + dd - 64);
        qf[c] = *reinterpret_cast<const bf16x8*>(src);
    }

    float m_run = -1e30f, l_run = 0.0f;
    f32x4 acc[4] = {};  // O accum: lane holds q=lg*4+r rows, d = dt*16+l15

    int kmax = q0 + 64;
    for (int kb = 0; kb < kmax; kb += 64) {
        __syncthreads();
        // stage K' [64][128]
#pragma unroll
        for (int i = 0; i < 4; i++) {
            int cid = i * 256 + t;
            int kr = cid >> 4, dd = (cid & 15) << 3;
            size_t gidx = ((size_t)(b * T_SEQ + kb + kr)) * DMODEL + h * DHEAD;
            const bf16* src = (dd < 64) ? (Kc + gidx + dd) : (Ks + gidx + dd - 64);
            *reinterpret_cast<bf16x8*>(&Klds[kr][dd]) = *reinterpret_cast<const bf16x8*>(src);
        }
        // stage V transposed [d][k]
#pragma unroll
        for (int i = 0; i < 2; i++) {
            int cid = i * 256 + t;
            int kr = cid >> 3, dd = (cid & 7) << 3;
            bf16x8 vv = *reinterpret_cast<const bf16x8*>(
                &V[((size_t)(b * T_SEQ + kb + kr)) * DMODEL + h * DHEAD + dd]);
#pragma unroll
            for (int e = 0; e < 8; e++) Vt[dd + e][kr] = vv[e];
        }
        __syncthreads();

#pragma unroll
        for (int sub = 0; sub < 2; sub++) {
            // S^T tiles: mfma(A=K'rows, B=Q) -> lane: col=q(l15), row=k(lg*4+r)
            f32x4 st[2] = {};
#pragma unroll
            for (int tt = 0; tt < 2; tt++) {
#pragma unroll
                for (int c = 0; c < 4; c++) {
                    bf16x8 kf = *reinterpret_cast<const bf16x8*>(
                        &Klds[sub * 32 + tt * 16 + l15][c * 32 + lg * 8]);
                    st[tt] = __builtin_amdgcn_mfma_f32_16x16x32_bf16(kf, qf[c], st[tt], 0, 0, 0);
                }
            }
            float s[8];
            float rm = -1e30f;
#pragma unroll
            for (int tt = 0; tt < 2; tt++)
#pragma unroll
                for (int r = 0; r < 4; r++) {
                    int kgl = kb + sub * 32 + tt * 16 + lg * 4 + r;
                    float sv = st[tt][r] * 0.125f;
                    if (kgl > qg) sv = -1e30f;
                    s[tt * 4 + r] = sv;
                    rm = fmaxf(rm, sv);
                }
            rm = fmaxf(rm, __shfl_xor(rm, 16));
            rm = fmaxf(rm, __shfl_xor(rm, 32));
            float m_new = fmaxf(m_run, rm);
            float sc = __expf(m_run - m_new);
            float p[8], rs = 0.0f;
#pragma unroll
            for (int j = 0; j < 8; j++) { p[j] = __expf(s[j] - m_new); rs += p[j]; }
            rs += __shfl_xor(rs, 16);
            rs += __shfl_xor(rs, 32);
            l_run = l_run * sc + rs;
            m_run = m_new;
            // rescale O (scale for q'=lg*4+r lives in lane q')
#pragma unroll
            for (int r = 0; r < 4; r++) {
                float oscr = __shfl(sc, lg * 4 + r);
#pragma unroll
                for (int dt = 0; dt < 4; dt++) acc[dt][r] *= oscr;
            }
            // write P (bf16) to per-wave LDS tile [q][k32]
#pragma unroll
            for (int tt = 0; tt < 2; tt++) {
                bf16x4 pk;
#pragma unroll
                for (int r = 0; r < 4; r++) pk[r] = (bf16)p[tt * 4 + r];
                *reinterpret_cast<bf16x4*>(&Plds[w][l15][tt * 16 + lg * 4]) = pk;
            }
            __syncthreads();
            // PV: O[q,d] += P[q,k32] * V[k32,d]
            bf16x8 paf = *reinterpret_cast<const bf16x8*>(&Plds[w][l15][lg * 8]);
#pragma unroll
            for (int dt = 0; dt < 4; dt++) {
                bf16x8 vf = *reinterpret_cast<const bf16x8*>(&Vt[dt * 16 + l15][sub * 32 + lg * 8]);
                acc[dt] = __builtin_amdgcn_mfma_f32_16x16x32_bf16(paf, vf, acc[dt], 0, 0, 0);
            }
            __syncthreads();
        }
    }

    float linv = 1.0f / l_run;  // stats for q=l15
#pragma unroll
    for (int r = 0; r < 4; r++) {
        float li = __shfl(linv, lg * 4 + r);
        int qr = q0 + w * 16 + lg * 4 + r;
        size_t obase = ((size_t)(b * T_SEQ + qr)) * DMODEL + h * DHEAD;
#pragma unroll
        for (int dt = 0; dt < 4; dt++)
            O[obase + dt * 16 + l15] = (bf16)(acc[dt][r] * li);
    }
}

// ---------------------------------------------------------------- launch
extern "C" void kernel_launch(void* const* d_in, const int* in_sizes, int n_in,
                              void* d_out, int out_size, void* d_ws, size_t ws_size,
                              hipStream_t stream) {
    const float* x = (const float*)d_in[0];
    const float* pos = (const float*)d_in[1];
    const float* Wqc = (const float*)d_in[2];  const float* bqc = (const float*)d_in[3];
    const float* Wkc = (const float*)d_in[4];  const float* bkc = (const float*)d_in[5];
    const float* Wqs = (const float*)d_in[6];  const float* bqs = (const float*)d_in[7];
    const float* Wks = (const float*)d_in[8];  const float* bks = (const float*)d_in[9];
    const float* Wv  = (const float*)d_in[10]; const float* bv  = (const float*)d_in[11];
    const float* Wo  = (const float*)d_in[12]; const float* bo  = (const float*)d_in[13];
    const float* ln1w = (const float*)d_in[14]; const float* ln1b = (const float*)d_in[15];
    const float* ln2w = (const float*)d_in[16]; const float* ln2b = (const float*)d_in[17];
    const float* Wf1 = (const float*)d_in[18]; const float* bf1 = (const float*)d_in[19];
    const float* Wf2 = (const float*)d_in[20]; const float* bf2 = (const float*)d_in[21];
    float* out = (float*)d_out;

    // workspace carve-up (all sizes 256B-aligned by construction)
    char* wsp = (char*)d_ws;
    size_t off = 0;
    auto alloc = [&](size_t bytes) { void* p = wsp + off; off += (bytes + 255) & ~(size_t)255; return p; };
    const size_t DD = (size_t)DMODEL * DMODEL;           // 1M
    const size_t RD = (size_t)NROWS * DMODEL;            // 4M
    bf16* WqcT = (bf16*)alloc(DD * 2);
    bf16* WkcT = (bf16*)alloc(DD * 2);
    bf16* WqsT = (bf16*)alloc(DD * 2);
    bf16* WksT = (bf16*)alloc(DD * 2);
    bf16* WvT  = (bf16*)alloc(DD * 2);
    bf16* WoT  = (bf16*)alloc(DD * 2);
    bf16* Wf1T = (bf16*)alloc((size_t)DMODEL * DFFN * 2);
    bf16* Wf2T = (bf16*)alloc((size_t)DMODEL * DFFN * 2);
    bf16* hb   = (bf16*)alloc(RD * 2);     // LN1(x)
    bf16* posb = (bf16*)alloc(RD * 2);     // pos_emb bf16
    bf16* Qcb  = (bf16*)alloc(RD * 2);
    bf16* Kcb  = (bf16*)alloc(RD * 2);
    bf16* Qsb  = (bf16*)alloc(RD * 2);
    bf16* Ksb  = (bf16*)alloc(RD * 2);
    bf16* Vb   = (bf16*)alloc(RD * 2);
    bf16* Ab   = (bf16*)alloc(RD * 2);     // attention out
    float* x2  = (float*)alloc(RD * 4);    // residual 1
    bf16* h2b  = (bf16*)alloc(RD * 2);     // LN2(x2)
    bf16* gb   = (bf16*)alloc((size_t)NROWS * DFFN * 2);  // gelu(ffn1)

    // 1) weight transposes -> bf16 [N][K]
    transpose_f32_to_bf16<<<dim3(DMODEL / 32, DMODEL / 32), 256, 0, stream>>>(Wqc, WqcT, DMODEL, DMODEL);
    transpose_f32_to_bf16<<<dim3(DMODEL / 32, DMODEL / 32), 256, 0, stream>>>(Wkc, WkcT, DMODEL, DMODEL);
    transpose_f32_to_bf16<<<dim3(DMODEL / 32, DMODEL / 32), 256, 0, stream>>>(Wqs, WqsT, DMODEL, DMODEL);
    transpose_f32_to_bf16<<<dim3(DMODEL / 32, DMODEL / 32), 256, 0, stream>>>(Wks, WksT, DMODEL, DMODEL);
    transpose_f32_to_bf16<<<dim3(DMODEL / 32, DMODEL / 32), 256, 0, stream>>>(Wv, WvT, DMODEL, DMODEL);
    transpose_f32_to_bf16<<<dim3(DMODEL / 32, DMODEL / 32), 256, 0, stream>>>(Wo, WoT, DMODEL, DMODEL);
    transpose_f32_to_bf16<<<dim3(DFFN / 32, DMODEL / 32), 256, 0, stream>>>(Wf1, Wf1T, DMODEL, DFFN);
    transpose_f32_to_bf16<<<dim3(DMODEL / 32, DFFN / 32), 256, 0, stream>>>(Wf2, Wf2T, DFFN, DMODEL);

    // 2) LN1 + pos cast
    layernorm_bf16<<<NROWS, 256, 0, stream>>>(x, ln1w, ln1b, hb);
    cast_f32_bf16<<<(RD / 4 + 255) / 256, 256, 0, stream>>>(pos, posb, RD / 4);

    // 3) QKV projections
    dim3 g1(DMODEL / 128, NROWS / 128);
    gemm_bf16<0><<<g1, 256, 0, stream>>>(hb,   WqcT, bqc, nullptr, Qcb, NROWS, DMODEL, DMODEL);
    gemm_bf16<0><<<g1, 256, 0, stream>>>(hb,   WkcT, bkc, nullptr, Kcb, NROWS, DMODEL, DMODEL);
    gemm_bf16<0><<<g1, 256, 0, stream>>>(posb, WqsT, bqs, nullptr, Qsb, NROWS, DMODEL, DMODEL);
    gemm_bf16<0><<<g1, 256, 0, stream>>>(posb, WksT, bks, nullptr, Ksb, NROWS, DMODEL, DMODEL);
    gemm_bf16<0><<<g1, 256, 0, stream>>>(hb,   WvT,  bv,  nullptr, Vb,  NROWS, DMODEL, DMODEL);

    // 4) flash attention
    flash_attn<<<dim3(T_SEQ / 64, NBATCH * NHEAD), 256, 0, stream>>>(Qcb, Kcb, Qsb, Ksb, Vb, Ab);

    // 5) output projection + residual -> x2 (f32)
    gemm_bf16<2><<<g1, 256, 0, stream>>>(Ab, WoT, bo, x, x2, NROWS, DMODEL, DMODEL);

    // 6) LN2
    layernorm_bf16<<<NROWS, 256, 0, stream>>>(x2, ln2w, ln2b, h2b);

    // 7) FFN1 + GELU
    gemm_bf16<1><<<dim3(DFFN / 128, NROWS / 128), 256, 0, stream>>>(h2b, Wf1T, bf1, nullptr, gb, NROWS, DFFN, DMODEL);

    // 8) FFN2 + residual -> out (f32)
    gemm_bf16<2><<<g1, 256, 0, stream>>>(gb, Wf2T, bf2, x2, out, NROWS, DMODEL, DFFN);
}

// Round 3
// 548.022 us; speedup vs baseline: 1.1793x; 1.1793x over previous
//
#include <hip/hip_runtime.h>
#include <hip/hip_bf16.h>

#define T_SEQ 2048
#define DMODEL 1024
#define NHEAD 16
#define DHEAD 64
#define NBATCH 2
#define NROWS (NBATCH * T_SEQ)   // 4096
#define DFFN (4 * DMODEL)        // 4096
#define S1 3072                  // fused [Qc|Kc|V] row stride
#define S2 2048                  // fused [Qs|Ks] row stride

typedef __bf16 bf16;
typedef __bf16 bf16x8 __attribute__((ext_vector_type(8)));
typedef __bf16 bf16x4 __attribute__((ext_vector_type(4)));
typedef float f32x4 __attribute__((ext_vector_type(4)));

__device__ __forceinline__ void gload_lds16(const void* g, void* l) {
    __builtin_amdgcn_global_load_lds((const __attribute__((address_space(1))) unsigned int*)g,
                                     (__attribute__((address_space(3))) unsigned int*)l, 16, 0, 0);
}

// ---------------------------------------------------------------- fused 6x [1024][1024] f32 -> bf16 transpose
struct TP6 { const float* src[6]; bf16* dst[6]; };
__global__ void transpose6(TP6 p) {
    __shared__ float tile[32][33];
    const float* in = p.src[blockIdx.z];
    bf16* out = p.dst[blockIdx.z];
    int k0 = blockIdx.y * 32, n0 = blockIdx.x * 32;
    int tx = threadIdx.x & 31, ty = threadIdx.x >> 5;
#pragma unroll
    for (int i = 0; i < 32; i += 8)
        tile[ty + i][tx] = in[(size_t)(k0 + ty + i) * 1024 + n0 + tx];
    __syncthreads();
#pragma unroll
    for (int i = 0; i < 32; i += 8)
        out[(size_t)(n0 + ty + i) * 1024 + k0 + tx] = (bf16)tile[tx][ty + i];
}

__global__ void transpose_f32_to_bf16(const float* __restrict__ in, bf16* __restrict__ out,
                                      int K, int N) {
    __shared__ float tile[32][33];
    int k0 = blockIdx.y * 32, n0 = blockIdx.x * 32;
    int tx = threadIdx.x & 31, ty = threadIdx.x >> 5;
#pragma unroll
    for (int i = 0; i < 32; i += 8)
        tile[ty + i][tx] = in[(size_t)(k0 + ty + i) * N + n0 + tx];
    __syncthreads();
#pragma unroll
    for (int i = 0; i < 32; i += 8)
        out[(size_t)(n0 + ty + i) * K + k0 + tx] = (bf16)tile[tx][ty + i];
}

__global__ void cast_f32_bf16(const float* __restrict__ in, bf16* __restrict__ out, int n4) {
    int i = blockIdx.x * blockDim.x + threadIdx.x;
    if (i >= n4) return;
    float4 v = reinterpret_cast<const float4*>(in)[i];
    bf16x4 o;
    o[0] = (bf16)v.x; o[1] = (bf16)v.y; o[2] = (bf16)v.z; o[3] = (bf16)v.w;
    reinterpret_cast<bf16x4*>(out)[i] = o;
}

__global__ void concat_bias3(const float* __restrict__ b0, const float* __restrict__ b1,
                             const float* __restrict__ b2, float* __restrict__ out, int n) {
    int i = blockIdx.x * 256 + threadIdx.x;
    if (i >= n) return;
    const float* src = (i < 1024) ? b0 : (i < 2048) ? b1 : b2;
    out[i] = src[i & 1023];
}

// ---------------------------------------------------------------- LayerNorm row (D=1024), out bf16
__global__ void layernorm_bf16(const float* __restrict__ x, const float* __restrict__ w,
                               const float* __restrict__ b, bf16* __restrict__ out) {
    int row = blockIdx.x;
    int t = threadIdx.x;
    const float* xr = x + (size_t)row * DMODEL;
    float4 v = reinterpret_cast<const float4*>(xr)[t];
    float s = v.x + v.y + v.z + v.w;
    float sq = v.x * v.x + v.y * v.y + v.z * v.z + v.w * v.w;
#pragma unroll
    for (int off = 1; off < 64; off <<= 1) {
        s += __shfl_xor(s, off);
        sq += __shfl_xor(sq, off);
    }
    __shared__ float ss[4], ssq[4];
    int wid = t >> 6;
    if ((t & 63) == 0) { ss[wid] = s; ssq[wid] = sq; }
    __syncthreads();
    s = ss[0] + ss[1] + ss[2] + ss[3];
    sq = ssq[0] + ssq[1] + ssq[2] + ssq[3];
    float mu = s * (1.0f / DMODEL);
    float var = sq * (1.0f / DMODEL) - mu * mu;
    float rstd = rsqrtf(var + 1e-5f);
    float4 wv = reinterpret_cast<const float4*>(w)[t];
    float4 bv = reinterpret_cast<const float4*>(b)[t];
    bf16x4 o;
    o[0] = (bf16)((v.x - mu) * rstd * wv.x + bv.x);
    o[1] = (bf16)((v.y - mu) * rstd * wv.y + bv.y);
    o[2] = (bf16)((v.z - mu) * rstd * wv.z + bv.z);
    o[3] = (bf16)((v.w - mu) * rstd * wv.w + bv.w);
    reinterpret_cast<bf16x4*>(out + (size_t)row * DMODEL)[t] = o;
}

// ---------------------------------------------------------------- GEMM (m97 structure): C[M,N] = A[M,K] * Bt[N,K]^T
// MODE 0: bf16 out  MODE 1: bf16 out + exact GELU  MODE 2: f32 out = v + bias + res
template <int BN, int MODE>
__global__ __launch_bounds__(256, 3) void gemm_glds(const bf16* __restrict__ A,
                                                    const bf16* __restrict__ Bt,
                                                    const float* __restrict__ bias,
                                                    const float* __restrict__ res,
                                                    void* __restrict__ Cout,
                                                    int M, int N, int K) {
    constexpr int BM = 128, BK = 32;
    constexpr int WN = BN / 2;        // per-wave cols (2x2 wave grid)
    constexpr int NB = BN / 64;       // B staging chunks per wave
    constexpr int NI = WN / 16;       // acc cols
    __shared__ __align__(16) bf16 As[BM * BK];
    __shared__ __align__(16) bf16 Bs[BN * BK];
    int m0 = blockIdx.y * BM, n0 = blockIdx.x * BN;
    int t = threadIdx.x, lane = t & 63, w = t >> 6;
    int wr = w >> 1, wc = w & 1;
    int l15 = lane & 15, lg = lane >> 4;
    int lr = lane >> 2, lc = (lane & 3) << 3;   // staging: 16 rows/chunk, 4 x 8-elem per row
    f32x4 acc[4][NI] = {};

    const bf16* Ab = A + (size_t)(m0 + lr) * K + lc;
    const bf16* Bb = Bt + (size_t)(n0 + lr) * K + lc;

    for (int kb = 0; kb < K; kb += BK) {
        __syncthreads();
#pragma unroll
        for (int i = 0; i < 2; i++) {
            int c = w * 2 + i;
            gload_lds16(Ab + (size_t)(c * 16) * K + kb, &As[c * 512]);
        }
#pragma unroll
        for (int i = 0; i < NB; i++) {
            int c = w * NB + i;
            gload_lds16(Bb + (size_t)(c * 16) * K + kb, &Bs[c * 512]);
        }
        __syncthreads();
        bf16x8 af[4], bfr[NI];
#pragma unroll
        for (int i = 0; i < 4; i++)
            af[i] = *(const bf16x8*)&As[(wr * 64 + i * 16 + l15) * BK + lg * 8];
#pragma unroll
        for (int i = 0; i < NI; i++)
            bfr[i] = *(const bf16x8*)&Bs[(wc * WN + i * 16 + l15) * BK + lg * 8];
#pragma unroll
        for (int mi = 0; mi < 4; mi++)
#pragma unroll
            for (int ni = 0; ni < NI; ni++)
                acc[mi][ni] = __builtin_amdgcn_mfma_f32_16x16x32_bf16(af[mi], bfr[ni], acc[mi][ni], 0, 0, 0);
    }

#pragma unroll
    for (int mi = 0; mi < 4; mi++) {
#pragma unroll
        for (int ni = 0; ni < NI; ni++) {
            int col = n0 + wc * WN + ni * 16 + l15;
            float bsv = bias[col];
#pragma unroll
            for (int r = 0; r < 4; r++) {
                int row = m0 + wr * 64 + mi * 16 + lg * 4 + r;
                float v = acc[mi][ni][r] + bsv;
                size_t idx = (size_t)row * N + col;
                if (MODE == 0) {
                    ((bf16*)Cout)[idx] = (bf16)v;
                } else if (MODE == 1) {
                    float g = 0.5f * v * (1.0f + erff(v * 0.70710678118654752f));
                    ((bf16*)Cout)[idx] = (bf16)g;
                } else {
                    ((float*)Cout)[idx] = v + res[idx];
                }
            }
        }
    }
}

// ---------------------------------------------------------------- flash attention, dual-QK (qk 128), causal
// grid (T/128, B*H), 256 threads. Wave w owns 32 q-rows (2 subtiles of 16).
__global__ __launch_bounds__(256, 2) void flash_attn(const bf16* __restrict__ QKV,
                                                     const bf16* __restrict__ QsKs,
                                                     bf16* __restrict__ O) {
    __shared__ __align__(16) bf16 Klds[64][136];      // [k][qk-dim concat], 272B rows
    __shared__ __align__(16) bf16 Vt[64][72];         // [d][k], 144B rows
    __shared__ __align__(16) bf16 Plds[4][2][16][48]; // per-wave, per-qt [q][k32], 96B rows

    int bh = blockIdx.y;
    int b = bh >> 4, h = bh & 15;
    int q0 = (gridDim.x - 1 - blockIdx.x) * 128;  // longest blocks first
    int t = threadIdx.x;
    int w = t >> 6, lane = t & 63;
    int l15 = lane & 15, lg = lane >> 4;
    int qw = q0 + w * 32;

    bf16x8 qf[2][4];
#pragma unroll
    for (int qt = 0; qt < 2; qt++) {
        size_t qrow = (size_t)(b * T_SEQ + qw + qt * 16 + l15);
        const bf16* qc = QKV + qrow * S1 + h * DHEAD;
        const bf16* qs = QsKs + qrow * S2 + h * DHEAD;
#pragma unroll
        for (int c = 0; c < 2; c++) {
            qf[qt][c]     = *(const bf16x8*)(qc + c * 32 + lg * 8);
            qf[qt][2 + c] = *(const bf16x8*)(qs + c * 32 + lg * 8);
        }
    }

    float m_run[2] = {-1e30f, -1e30f}, l_run[2] = {0.0f, 0.0f};
    f32x4 acc[2][4] = {};

    int kmax = q0 + 128;
    for (int kb = 0; kb < kmax; kb += 64) {
        __syncthreads();
        // stage K' = [Kc|Ks] rows
#pragma unroll
        for (int i = 0; i < 4; i++) {
            int cid = i * 256 + t;
            int kr = cid >> 4, dd = (cid & 15) << 3;
            size_t rowi = (size_t)(b * T_SEQ + kb + kr);
            const bf16* src = (dd < 64) ? (QKV + rowi * S1 + 1024 + h * DHEAD + dd)
                                        : (QsKs + rowi * S2 + 1024 + h * DHEAD + dd - 64);
            *(bf16x8*)&Klds[kr][dd] = *(const bf16x8*)src;
        }
        // stage V transposed with rotated writes (conflict-free)
#pragma unroll
        for (int i = 0; i < 2; i++) {
            int cid = i * 256 + t;
            int kr = cid >> 3, j0 = cid & 7;
            bf16x8 vv = *(const bf16x8*)(QKV + (size_t)(b * T_SEQ + kb + kr) * S1 + 2048 + h * DHEAD + j0 * 8);
#pragma unroll
            for (int e = 0; e < 8; e++) {
                int j = (e + j0) & 7;
                Vt[j0 * 8 + j][kr] = vv[j];
            }
        }
        __syncthreads();

#pragma unroll
        for (int sub = 0; sub < 2; sub++) {
            if (kb + sub * 32 > qw + 31) continue;  // whole wave-tile masked
            bf16x8 kf[2][4];
#pragma unroll
            for (int tt = 0; tt < 2; tt++)
#pragma unroll
                for (int c = 0; c < 4; c++)
                    kf[tt][c] = *(const bf16x8*)&Klds[sub * 32 + tt * 16 + l15][c * 32 + lg * 8];
#pragma unroll
            for (int qt = 0; qt < 2; qt++) {
                if (kb + sub * 32 > qw + qt * 16 + 15) continue;  // this q-subtile masked
                int qg = qw + qt * 16 + l15;
                f32x4 st[2] = {};
#pragma unroll
                for (int tt = 0; tt < 2; tt++)
#pragma unroll
                    for (int c = 0; c < 4; c++)
                        st[tt] = __builtin_amdgcn_mfma_f32_16x16x32_bf16(kf[tt][c], qf[qt][c], st[tt], 0, 0, 0);
                float s[8], rm = -1e30f;
#pragma unroll
                for (int tt = 0; tt < 2; tt++)
#pragma unroll
                    for (int r = 0; r < 4; r++) {
                        int kgl = kb + sub * 32 + tt * 16 + lg * 4 + r;
                        float sv = st[tt][r] * 0.125f;
                        if (kgl > qg) sv = -1e30f;
                        s[tt * 4 + r] = sv;
                        rm = fmaxf(rm, sv);
                    }
                rm = fmaxf(rm, __shfl_xor(rm, 16));
                rm = fmaxf(rm, __shfl_xor(rm, 32));
                float m_new = fmaxf(m_run[qt], rm);
                float sc = __expf(m_run[qt] - m_new);
                float p[8], rs = 0.0f;
#pragma unroll
                for (int j = 0; j < 8; j++) { p[j] = __expf(s[j] - m_new); rs += p[j]; }
                rs += __shfl_xor(rs, 16);
                rs += __shfl_xor(rs, 32);
                l_run[qt] = l_run[qt] * sc + rs;
                m_run[qt] = m_new;
#pragma unroll
                for (int r = 0; r < 4; r++) {
                    float oscr = __shfl(sc, lg * 4 + r);
#pragma unroll
                    for (int dt = 0; dt < 4; dt++) acc[qt][dt][r] *= oscr;
                }
                bf16x4 pk0, pk1;
#pragma unroll
                for (int r = 0; r < 4; r++) { pk0[r] = (bf16)p[r]; pk1[r] = (bf16)p[4 + r]; }
                *(bf16x4*)&Plds[w][qt][l15][lg * 4] = pk0;
                *(bf16x4*)&Plds[w][qt][l15][16 + lg * 4] = pk1;
                asm volatile("s_waitcnt lgkmcnt(0)" ::: "memory");
                __builtin_amdgcn_sched_barrier(0);
                bf16x8 paf = *(const bf16x8*)&Plds[w][qt][l15][lg * 8];
#pragma unroll
                for (int dt = 0; dt < 4; dt++) {
                    bf16x8 vf = *(const bf16x8*)&Vt[dt * 16 + l15][sub * 32 + lg * 8];
                    acc[qt][dt] = __builtin_amdgcn_mfma_f32_16x16x32_bf16(paf, vf, acc[qt][dt], 0, 0, 0);
                }
            }
        }
    }

#pragma unroll
    for (int qt = 0; qt < 2; qt++) {
        float linv = 1.0f / l_run[qt];
#pragma unroll
        for (int r = 0; r < 4; r++) {
            float li = __shfl(linv, lg * 4 + r);
            size_t qrow = (size_t)(b * T_SEQ + qw + qt * 16 + lg * 4 + r);
#pragma unroll
            for (int dt = 0; dt < 4; dt++)
                O[qrow * DMODEL + h * DHEAD + dt * 16 + l15] = (bf16)(acc[qt][dt][r] * li);
        }
    }
}

// ---------------------------------------------------------------- launch
extern "C" void kernel_launch(void* const* d_in, const int* in_sizes, int n_in,
                              void* d_out, int out_size, void* d_ws, size_t ws_size,
                              hipStream_t stream) {
    const float* x = (const float*)d_in[0];
    const float* pos = (const float*)d_in[1];
    const float* Wqc = (const float*)d_in[2];  const float* bqc = (const float*)d_in[3];
    const float* Wkc = (const float*)d_in[4];  const float* bkc = (const float*)d_in[5];
    const float* Wqs = (const float*)d_in[6];  const float* bqs = (const float*)d_in[7];
    const float* Wks = (const float*)d_in[8];  const float* bks = (const float*)d_in[9];
    const float* Wv  = (const float*)d_in[10]; const float* bv  = (const float*)d_in[11];
    const float* Wo  = (const float*)d_in[12]; const float* bo  = (const float*)d_in[13];
    const float* ln1w = (const float*)d_in[14]; const float* ln1b = (const float*)d_in[15];
    const float* ln2w = (const float*)d_in[16]; const float* ln2b = (const float*)d_in[17];
    const float* Wf1 = (const float*)d_in[18]; const float* bf1 = (const float*)d_in[19];
    const float* Wf2 = (const float*)d_in[20]; const float* bf2 = (const float*)d_in[21];
    float* out = (float*)d_out;

    char* wsp = (char*)d_ws;
    size_t off = 0;
    auto alloc = [&](size_t bytes) { void* p = wsp + off; off += (bytes + 255) & ~(size_t)255; return p; };
    const size_t DD = (size_t)DMODEL * DMODEL;
    const size_t RD = (size_t)NROWS * DMODEL;
    bf16* Wcat1 = (bf16*)alloc(3 * DD * 2);     // [Qc|Kc|V] transposed, [3072][1024]
    bf16* Wcat2 = (bf16*)alloc(2 * DD * 2);     // [Qs|Ks] transposed, [2048][1024]
    bf16* WoT  = (bf16*)alloc(DD * 2);
    bf16* Wf1T = (bf16*)alloc((size_t)DMODEL * DFFN * 2);
    bf16* Wf2T = (bf16*)alloc((size_t)DMODEL * DFFN * 2);
    float* bc1 = (float*)alloc(3 * DMODEL * 4); // [bqc|bkc|bv]
    float* bc2 = (float*)alloc(2 * DMODEL * 4); // [bqs|bks]
    bf16* hb   = (bf16*)alloc(RD * 2);
    bf16* posb = (bf16*)alloc(RD * 2);
    bf16* C1   = (bf16*)alloc((size_t)NROWS * S1 * 2);  // [Qc|Kc|V]
    bf16* C2   = (bf16*)alloc((size_t)NROWS * S2 * 2);  // [Qs|Ks]
    bf16* Ab   = (bf16*)alloc(RD * 2);
    float* x2  = (float*)alloc(RD * 4);
    bf16* h2b  = (bf16*)alloc(RD * 2);
    bf16* gb   = (bf16*)alloc((size_t)NROWS * DFFN * 2);

    // 1) weight transposes
    TP6 tp;
    tp.src[0] = Wqc; tp.dst[0] = Wcat1;
    tp.src[1] = Wkc; tp.dst[1] = Wcat1 + DD;
    tp.src[2] = Wv;  tp.dst[2] = Wcat1 + 2 * DD;
    tp.src[3] = Wqs; tp.dst[3] = Wcat2;
    tp.src[4] = Wks; tp.dst[4] = Wcat2 + DD;
    tp.src[5] = Wo;  tp.dst[5] = WoT;
    transpose6<<<dim3(32, 32, 6), 256, 0, stream>>>(tp);
    transpose_f32_to_bf16<<<dim3(DFFN / 32, DMODEL / 32), 256, 0, stream>>>(Wf1, Wf1T, DMODEL, DFFN);
    transpose_f32_to_bf16<<<dim3(DMODEL / 32, DFFN / 32), 256, 0, stream>>>(Wf2, Wf2T, DFFN, DMODEL);
    concat_bias3<<<12, 256, 0, stream>>>(bqc, bkc, bv, bc1, 3 * DMODEL);
    concat_bias3<<<8, 256, 0, stream>>>(bqs, bks, bqs, bc2, 2 * DMODEL);

    // 2) LN1 + pos cast
    layernorm_bf16<<<NROWS, 256, 0, stream>>>(x, ln1w, ln1b, hb);
    cast_f32_bf16<<<(RD / 4 + 255) / 256, 256, 0, stream>>>(pos, posb, RD / 4);

    // 3) fused projections
    gemm_glds<128, 0><<<dim3(S1 / 128, NROWS / 128), 256, 0, stream>>>(hb, Wcat1, bc1, nullptr, C1, NROWS, S1, DMODEL);
    gemm_glds<128, 0><<<dim3(S2 / 128, NROWS / 128), 256, 0, stream>>>(posb, Wcat2, bc2, nullptr, C2, NROWS, S2, DMODEL);

    // 4) flash attention
    flash_attn<<<dim3(T_SEQ / 128, NBATCH * NHEAD), 256, 0, stream>>>(C1, C2, Ab);

    // 5) Wo + residual -> x2 (f32)
    gemm_glds<64, 2><<<dim3(DMODEL / 64, NROWS / 128), 256, 0, stream>>>(Ab, WoT, bo, x, x2, NROWS, DMODEL, DMODEL);

    // 6) LN2
    layernorm_bf16<<<NROWS, 256, 0, stream>>>(x2, ln2w, ln2b, h2b);

    // 7) FFN1 + GELU
    gemm_glds<128, 1><<<dim3(DFFN / 128, NROWS / 128), 256, 0, stream>>>(h2b, Wf1T, bf1, nullptr, gb, NROWS, DFFN, DMODEL);

    // 8) FFN2 + residual -> out (f32)
    gemm_glds<64, 2><<<dim3(DMODEL / 64, NROWS / 128), 256, 0, stream>>>(gb, Wf2T, bf2, x2, out, NROWS, DMODEL, DFFN);
}

// Round 4
// 499.605 us; speedup vs baseline: 1.2936x; 1.0969x over previous
//
#include <hip/hip_runtime.h>
#include <hip/hip_bf16.h>

#define T_SEQ 2048
#define DMODEL 1024
#define NHEAD 16
#define DHEAD 64
#define NBATCH 2
#define NROWS (NBATCH * T_SEQ)   // 4096
#define DFFN (4 * DMODEL)        // 4096
#define S1 3072                  // fused [Qc|Kc|V] row stride
#define S2 2048                  // fused [Qs|Ks] row stride

typedef __bf16 bf16;
typedef __bf16 bf16x8 __attribute__((ext_vector_type(8)));
typedef __bf16 bf16x4 __attribute__((ext_vector_type(4)));
typedef float f32x4 __attribute__((ext_vector_type(4)));

__device__ __forceinline__ void gload_lds16(const void* g, void* l) {
    __builtin_amdgcn_global_load_lds((const __attribute__((address_space(1))) unsigned int*)g,
                                     (__attribute__((address_space(3))) unsigned int*)l, 16, 0, 0);
}

// ---------------------------------------------------------------- fused 6x [1024][1024] f32 -> bf16 transpose
struct TP6 { const float* src[6]; bf16* dst[6]; };
__global__ void transpose6(TP6 p) {
    __shared__ float tile[32][33];
    const float* in = p.src[blockIdx.z];
    bf16* out = p.dst[blockIdx.z];
    int k0 = blockIdx.y * 32, n0 = blockIdx.x * 32;
    int tx = threadIdx.x & 31, ty = threadIdx.x >> 5;
#pragma unroll
    for (int i = 0; i < 32; i += 8)
        tile[ty + i][tx] = in[(size_t)(k0 + ty + i) * 1024 + n0 + tx];
    __syncthreads();
#pragma unroll
    for (int i = 0; i < 32; i += 8)
        out[(size_t)(n0 + ty + i) * 1024 + k0 + tx] = (bf16)tile[tx][ty + i];
}

__global__ void transpose_f32_to_bf16(const float* __restrict__ in, bf16* __restrict__ out,
                                      int K, int N) {
    __shared__ float tile[32][33];
    int k0 = blockIdx.y * 32, n0 = blockIdx.x * 32;
    int tx = threadIdx.x & 31, ty = threadIdx.x >> 5;
#pragma unroll
    for (int i = 0; i < 32; i += 8)
        tile[ty + i][tx] = in[(size_t)(k0 + ty + i) * N + n0 + tx];
    __syncthreads();
#pragma unroll
    for (int i = 0; i < 32; i += 8)
        out[(size_t)(n0 + ty + i) * K + k0 + tx] = (bf16)tile[tx][ty + i];
}

__global__ void cast_f32_bf16(const float* __restrict__ in, bf16* __restrict__ out, int n4) {
    int i = blockIdx.x * blockDim.x + threadIdx.x;
    if (i >= n4) return;
    float4 v = reinterpret_cast<const float4*>(in)[i];
    bf16x4 o;
    o[0] = (bf16)v.x; o[1] = (bf16)v.y; o[2] = (bf16)v.z; o[3] = (bf16)v.w;
    reinterpret_cast<bf16x4*>(out)[i] = o;
}

__global__ void concat_bias3(const float* __restrict__ b0, const float* __restrict__ b1,
                             const float* __restrict__ b2, float* __restrict__ out, int n) {
    int i = blockIdx.x * 256 + threadIdx.x;
    if (i >= n) return;
    const float* src = (i < 1024) ? b0 : (i < 2048) ? b1 : b2;
    out[i] = src[i & 1023];
}

// ---------------------------------------------------------------- LayerNorm row (D=1024), out bf16
__global__ void layernorm_bf16(const float* __restrict__ x, const float* __restrict__ w,
                               const float* __restrict__ b, bf16* __restrict__ out) {
    int row = blockIdx.x;
    int t = threadIdx.x;
    const float* xr = x + (size_t)row * DMODEL;
    float4 v = reinterpret_cast<const float4*>(xr)[t];
    float s = v.x + v.y + v.z + v.w;
    float sq = v.x * v.x + v.y * v.y + v.z * v.z + v.w * v.w;
#pragma unroll
    for (int off = 1; off < 64; off <<= 1) {
        s += __shfl_xor(s, off);
        sq += __shfl_xor(sq, off);
    }
    __shared__ float ss[4], ssq[4];
    int wid = t >> 6;
    if ((t & 63) == 0) { ss[wid] = s; ssq[wid] = sq; }
    __syncthreads();
    s = ss[0] + ss[1] + ss[2] + ss[3];
    sq = ssq[0] + ssq[1] + ssq[2] + ssq[3];
    float mu = s * (1.0f / DMODEL);
    float var = sq * (1.0f / DMODEL) - mu * mu;
    float rstd = rsqrtf(var + 1e-5f);
    float4 wv = reinterpret_cast<const float4*>(w)[t];
    float4 bv = reinterpret_cast<const float4*>(b)[t];
    bf16x4 o;
    o[0] = (bf16)((v.x - mu) * rstd * wv.x + bv.x);
    o[1] = (bf16)((v.y - mu) * rstd * wv.y + bv.y);
    o[2] = (bf16)((v.z - mu) * rstd * wv.z + bv.z);
    o[3] = (bf16)((v.w - mu) * rstd * wv.w + bv.w);
    reinterpret_cast<bf16x4*>(out + (size_t)row * DMODEL)[t] = o;
}

// ---------------------------------------------------------------- GEMM (m97 structure + XCD swizzle)
// MODE 0: bf16 out  MODE 1: bf16 out + exact GELU  MODE 2: f32 out = v + bias + res
template <int BN, int MODE>
__global__ __launch_bounds__(256, 3) void gemm_glds(const bf16* __restrict__ A,
                                                    const bf16* __restrict__ Bt,
                                                    const float* __restrict__ bias,
                                                    const float* __restrict__ res,
                                                    void* __restrict__ Cout,
                                                    int M, int N, int K) {
    constexpr int BM = 128, BK = 32;
    constexpr int WN = BN / 2;        // per-wave cols (2x2 wave grid)
    constexpr int NB = BN / 64;       // B staging chunks per wave
    constexpr int NI = WN / 16;       // acc cols
    __shared__ __align__(16) bf16 As[BM * BK];
    __shared__ __align__(16) bf16 Bs[BN * BK];
    // bijective XCD swizzle (all our grids are %8==0): contiguous tile chunk per XCD
    int lin = blockIdx.y * gridDim.x + blockIdx.x;
    int cpx = (gridDim.x * gridDim.y) >> 3;
    int swz = (lin & 7) * cpx + (lin >> 3);
    int bx = swz % gridDim.x, by = swz / gridDim.x;
    int m0 = by * BM, n0 = bx * BN;
    int t = threadIdx.x, lane = t & 63, w = t >> 6;
    int wr = w >> 1, wc = w & 1;
    int l15 = lane & 15, lg = lane >> 4;
    int lr = lane >> 2, lc = (lane & 3) << 3;   // staging: 16 rows/chunk, 4 x 8-elem per row
    f32x4 acc[4][NI] = {};

    const bf16* Ab = A + (size_t)(m0 + lr) * K + lc;
    const bf16* Bb = Bt + (size_t)(n0 + lr) * K + lc;

    for (int kb = 0; kb < K; kb += BK) {
        __syncthreads();
#pragma unroll
        for (int i = 0; i < 2; i++) {
            int c = w * 2 + i;
            gload_lds16(Ab + (size_t)(c * 16) * K + kb, &As[c * 512]);
        }
#pragma unroll
        for (int i = 0; i < NB; i++) {
            int c = w * NB + i;
            gload_lds16(Bb + (size_t)(c * 16) * K + kb, &Bs[c * 512]);
        }
        __syncthreads();
        bf16x8 af[4], bfr[NI];
#pragma unroll
        for (int i = 0; i < 4; i++)
            af[i] = *(const bf16x8*)&As[(wr * 64 + i * 16 + l15) * BK + lg * 8];
#pragma unroll
        for (int i = 0; i < NI; i++)
            bfr[i] = *(const bf16x8*)&Bs[(wc * WN + i * 16 + l15) * BK + lg * 8];
#pragma unroll
        for (int mi = 0; mi < 4; mi++)
#pragma unroll
            for (int ni = 0; ni < NI; ni++)
                acc[mi][ni] = __builtin_amdgcn_mfma_f32_16x16x32_bf16(af[mi], bfr[ni], acc[mi][ni], 0, 0, 0);
    }

#pragma unroll
    for (int mi = 0; mi < 4; mi++) {
#pragma unroll
        for (int ni = 0; ni < NI; ni++) {
            int col = n0 + wc * WN + ni * 16 + l15;
            float bsv = bias[col];
#pragma unroll
            for (int r = 0; r < 4; r++) {
                int row = m0 + wr * 64 + mi * 16 + lg * 4 + r;
                float v = acc[mi][ni][r] + bsv;
                size_t idx = (size_t)row * N + col;
                if (MODE == 0) {
                    ((bf16*)Cout)[idx] = (bf16)v;
                } else if (MODE == 1) {
                    float g = 0.5f * v * (1.0f + erff(v * 0.70710678118654752f));
                    ((bf16*)Cout)[idx] = (bf16)g;
                } else {
                    ((float*)Cout)[idx] = v + res[idx];
                }
            }
        }
    }
}

// ---------------------------------------------------------------- flash attention, dual-QK (qk 128), causal
// grid (T/64, B*H), 256 threads. Wave w owns 16 q-rows. Defer-max softmax + async K/V prefetch.
__global__ __launch_bounds__(256, 4) void flash_attn(const bf16* __restrict__ QKV,
                                                     const bf16* __restrict__ QsKs,
                                                     bf16* __restrict__ O) {
    __shared__ __align__(16) bf16 Klds[64][136];   // [k][qk-dim concat]
    __shared__ __align__(16) bf16 Vt[64][72];      // [d][k]
    __shared__ __align__(16) bf16 Plds[4][16][56]; // per-wave [q][k32], 112B rows

    int bh = blockIdx.y;
    int b = bh >> 4, h = bh & 15;
    int q0 = (gridDim.x - 1 - blockIdx.x) * 64;  // longest blocks first
    int t = threadIdx.x;
    int w = t >> 6, lane = t & 63;
    int l15 = lane & 15, lg = lane >> 4;
    int qw = q0 + w * 16;
    int qg = qw + l15;          // this lane's q row (softmax stats column)

    // Q' fragments (qk-dim 128 = 4 chunks of 32) in registers
    size_t qrow = (size_t)(b * T_SEQ + qg);
    const bf16* qcp = QKV + qrow * S1 + h * DHEAD;
    const bf16* qsp = QsKs + qrow * S2 + h * DHEAD;
    bf16x8 qf[4];
#pragma unroll
    for (int c = 0; c < 2; c++) {
        qf[c]     = *(const bf16x8*)(qcp + c * 32 + lg * 8);
        qf[2 + c] = *(const bf16x8*)(qsp + c * 32 + lg * 8);
    }

    float m_run = -1e30f, l_part = 0.0f;
    f32x4 acc[4] = {};

    // staging maps
    int krow = t >> 4;                 // 0..15
    int kdd = (t & 15) << 3;           // 0..120
    int vr = t >> 3, j0 = t & 7;       // V: row base, rotation

    const bf16* kcb = QKV + (size_t)(b * T_SEQ) * S1 + 1024 + h * DHEAD;
    const bf16* ksb = QsKs + (size_t)(b * T_SEQ) * S2 + 1024 + h * DHEAD;
    const bf16* vb  = QKV + (size_t)(b * T_SEQ) * S1 + 2048 + h * DHEAD + j0 * 8;
    const bf16* ksrc = (kdd < 64) ? (kcb + kdd) : (ksb + kdd - 64);
    size_t kstride = (kdd < 64) ? S1 : S2;

    int nt = q0 / 64 + 1;
    bf16x8 kreg[4], vreg[2];
#pragma unroll
    for (int i = 0; i < 4; i++) kreg[i] = *(const bf16x8*)(ksrc + (size_t)(i * 16 + krow) * kstride);
#pragma unroll
    for (int i = 0; i < 2; i++) vreg[i] = *(const bf16x8*)(vb + (size_t)(i * 32 + vr) * S1);

    for (int it = 0; it < nt; ++it) {
        int kb = it * 64;
        __syncthreads();   // previous compute done; LDS free
#pragma unroll
        for (int i = 0; i < 4; i++) *(bf16x8*)&Klds[i * 16 + krow][kdd] = kreg[i];
#pragma unroll
        for (int i = 0; i < 2; i++) {
            int r = i * 32 + vr;
#pragma unroll
            for (int e = 0; e < 8; e++) {
                int j = (e + j0) & 7;
                Vt[j0 * 8 + j][r] = vreg[i][j];
            }
        }
        __syncthreads();
        if (it + 1 < nt) {   // prefetch next tile (latency hides under compute)
            int kn = kb + 64;
#pragma unroll
            for (int i = 0; i < 4; i++) kreg[i] = *(const bf16x8*)(ksrc + (size_t)(kn + i * 16 + krow) * kstride);
#pragma unroll
            for (int i = 0; i < 2; i++) vreg[i] = *(const bf16x8*)(vb + (size_t)(kn + i * 32 + vr) * S1);
        }

#pragma unroll
        for (int sub = 0; sub < 2; sub++) {
            if (kb + sub * 32 > qw + 15) break;  // fully masked for this wave
            // QK^T (swapped): lane holds col=q(l15), row=k(lg*4+r)
            f32x4 st[2];
            __builtin_amdgcn_s_setprio(1);
#pragma unroll
            for (int tt = 0; tt < 2; tt++) {
                f32x4 z = {};
#pragma unroll
                for (int c = 0; c < 4; c++) {
                    bf16x8 kf = *(const bf16x8*)&Klds[sub * 32 + tt * 16 + l15][c * 32 + lg * 8];
                    z = __builtin_amdgcn_mfma_f32_16x16x32_bf16(kf, qf[c], z, 0, 0, 0);
                }
                st[tt] = z;
            }
            __builtin_amdgcn_s_setprio(0);
            float s[8], lm = -1e30f;
#pragma unroll
            for (int tt = 0; tt < 2; tt++)
#pragma unroll
                for (int r = 0; r < 4; r++) {
                    int kgl = kb + sub * 32 + tt * 16 + lg * 4 + r;
                    float sv = st[tt][r] * 0.125f;
                    if (kgl > qg) sv = -1e30f;
                    s[tt * 4 + r] = sv;
                    lm = fmaxf(lm, sv);
                }
            // defer-max: full rescale path only when max grew > 8
            if (__any(lm > m_run + 8.0f)) {
                float rm = lm;
                rm = fmaxf(rm, __shfl_xor(rm, 16));
                rm = fmaxf(rm, __shfl_xor(rm, 32));
                float m_new = fmaxf(m_run, rm);
                float sc = __expf(m_run - m_new);
                l_part *= sc;
#pragma unroll
                for (int r = 0; r < 4; r++) {
                    float oscr = __shfl(sc, lg * 4 + r);
#pragma unroll
                    for (int dt = 0; dt < 4; dt++) acc[dt][r] *= oscr;
                }
                m_run = m_new;
            }
            float p[8];
#pragma unroll
            for (int j = 0; j < 8; j++) { p[j] = __expf(s[j] - m_run); l_part += p[j]; }
            bf16x4 pk0, pk1;
#pragma unroll
            for (int r = 0; r < 4; r++) { pk0[r] = (bf16)p[r]; pk1[r] = (bf16)p[4 + r]; }
            *(bf16x4*)&Plds[w][l15][lg * 4] = pk0;
            *(bf16x4*)&Plds[w][l15][16 + lg * 4] = pk1;
            asm volatile("s_waitcnt lgkmcnt(0)" ::: "memory");
            __builtin_amdgcn_sched_barrier(0);
            bf16x8 paf = *(const bf16x8*)&Plds[w][l15][lg * 8];
            __builtin_amdgcn_s_setprio(1);
#pragma unroll
            for (int dt = 0; dt < 4; dt++) {
                bf16x8 vf = *(const bf16x8*)&Vt[dt * 16 + l15][sub * 32 + lg * 8];
                acc[dt] = __builtin_amdgcn_mfma_f32_16x16x32_bf16(paf, vf, acc[dt], 0, 0, 0);
            }
            __builtin_amdgcn_s_setprio(0);
        }
    }

    float l = l_part;
    l += __shfl_xor(l, 16);
    l += __shfl_xor(l, 32);
    float linv = 1.0f / l;   // for q=l15
#pragma unroll
    for (int r = 0; r < 4; r++) {
        float li = __shfl(linv, lg * 4 + r);
        size_t orow = (size_t)(b * T_SEQ + qw + lg * 4 + r);
#pragma unroll
        for (int dt = 0; dt < 4; dt++)
            O[orow * DMODEL + h * DHEAD + dt * 16 + l15] = (bf16)(acc[dt][r] * li);
    }
}

// ---------------------------------------------------------------- launch
extern "C" void kernel_launch(void* const* d_in, const int* in_sizes, int n_in,
                              void* d_out, int out_size, void* d_ws, size_t ws_size,
                              hipStream_t stream) {
    const float* x = (const float*)d_in[0];
    const float* pos = (const float*)d_in[1];
    const float* Wqc = (const float*)d_in[2];  const float* bqc = (const float*)d_in[3];
    const float* Wkc = (const float*)d_in[4];  const float* bkc = (const float*)d_in[5];
    const float* Wqs = (const float*)d_in[6];  const float* bqs = (const float*)d_in[7];
    const float* Wks = (const float*)d_in[8];  const float* bks = (const float*)d_in[9];
    const float* Wv  = (const float*)d_in[10]; const float* bv  = (const float*)d_in[11];
    const float* Wo  = (const float*)d_in[12]; const float* bo  = (const float*)d_in[13];
    const float* ln1w = (const float*)d_in[14]; const float* ln1b = (const float*)d_in[15];
    const float* ln2w = (const float*)d_in[16]; const float* ln2b = (const float*)d_in[17];
    const float* Wf1 = (const float*)d_in[18]; const float* bf1 = (const float*)d_in[19];
    const float* Wf2 = (const float*)d_in[20]; const float* bf2 = (const float*)d_in[21];
    float* out = (float*)d_out;

    char* wsp = (char*)d_ws;
    size_t off = 0;
    auto alloc = [&](size_t bytes) { void* p = wsp + off; off += (bytes + 255) & ~(size_t)255; return p; };
    const size_t DD = (size_t)DMODEL * DMODEL;
    const size_t RD = (size_t)NROWS * DMODEL;
    bf16* Wcat1 = (bf16*)alloc(3 * DD * 2);     // [Qc|Kc|V] transposed
    bf16* Wcat2 = (bf16*)alloc(2 * DD * 2);     // [Qs|Ks] transposed
    bf16* WoT  = (bf16*)alloc(DD * 2);
    bf16* Wf1T = (bf16*)alloc((size_t)DMODEL * DFFN * 2);
    bf16* Wf2T = (bf16*)alloc((size_t)DMODEL * DFFN * 2);
    float* bc1 = (float*)alloc(3 * DMODEL * 4);
    float* bc2 = (float*)alloc(2 * DMODEL * 4);
    bf16* hb   = (bf16*)alloc(RD * 2);
    bf16* posb = (bf16*)alloc(RD * 2);
    bf16* C1   = (bf16*)alloc((size_t)NROWS * S1 * 2);  // [Qc|Kc|V]
    bf16* C2   = (bf16*)alloc((size_t)NROWS * S2 * 2);  // [Qs|Ks]
    bf16* Ab   = (bf16*)alloc(RD * 2);
    float* x2  = (float*)alloc(RD * 4);
    bf16* h2b  = (bf16*)alloc(RD * 2);
    bf16* gb   = (bf16*)alloc((size_t)NROWS * DFFN * 2);

    // 1) weight transposes
    TP6 tp;
    tp.src[0] = Wqc; tp.dst[0] = Wcat1;
    tp.src[1] = Wkc; tp.dst[1] = Wcat1 + DD;
    tp.src[2] = Wv;  tp.dst[2] = Wcat1 + 2 * DD;
    tp.src[3] = Wqs; tp.dst[3] = Wcat2;
    tp.src[4] = Wks; tp.dst[4] = Wcat2 + DD;
    tp.src[5] = Wo;  tp.dst[5] = WoT;
    transpose6<<<dim3(32, 32, 6), 256, 0, stream>>>(tp);
    transpose_f32_to_bf16<<<dim3(DFFN / 32, DMODEL / 32), 256, 0, stream>>>(Wf1, Wf1T, DMODEL, DFFN);
    transpose_f32_to_bf16<<<dim3(DMODEL / 32, DFFN / 32), 256, 0, stream>>>(Wf2, Wf2T, DFFN, DMODEL);
    concat_bias3<<<12, 256, 0, stream>>>(bqc, bkc, bv, bc1, 3 * DMODEL);
    concat_bias3<<<8, 256, 0, stream>>>(bqs, bks, bqs, bc2, 2 * DMODEL);

    // 2) LN1 + pos cast
    layernorm_bf16<<<NROWS, 256, 0, stream>>>(x, ln1w, ln1b, hb);
    cast_f32_bf16<<<(RD / 4 + 255) / 256, 256, 0, stream>>>(pos, posb, RD / 4);

    // 3) fused projections
    gemm_glds<128, 0><<<dim3(S1 / 128, NROWS / 128), 256, 0, stream>>>(hb, Wcat1, bc1, nullptr, C1, NROWS, S1, DMODEL);
    gemm_glds<128, 0><<<dim3(S2 / 128, NROWS / 128), 256, 0, stream>>>(posb, Wcat2, bc2, nullptr, C2, NROWS, S2, DMODEL);

    // 4) flash attention
    flash_attn<<<dim3(T_SEQ / 64, NBATCH * NHEAD), 256, 0, stream>>>(C1, C2, Ab);

    // 5) Wo + residual -> x2 (f32)
    gemm_glds<64, 2><<<dim3(DMODEL / 64, NROWS / 128), 256, 0, stream>>>(Ab, WoT, bo, x, x2, NROWS, DMODEL, DMODEL);

    // 6) LN2
    layernorm_bf16<<<NROWS, 256, 0, stream>>>(x2, ln2w, ln2b, h2b);

    // 7) FFN1 + GELU
    gemm_glds<128, 1><<<dim3(DFFN / 128, NROWS / 128), 256, 0, stream>>>(h2b, Wf1T, bf1, nullptr, gb, NROWS, DFFN, DMODEL);

    // 8) FFN2 + residual -> out (f32)
    gemm_glds<64, 2><<<dim3(DMODEL / 64, NROWS / 128), 256, 0, stream>>>(gb, Wf2T, bf2, x2, out, NROWS, DMODEL, DFFN);
}